// Round 6
// baseline (235.402 us; speedup 1.0000x reference)
//
#include <hip/hip_runtime.h>

// EMA along T: y[0]=x[0]; y[t] = s*x[t] + (1-s)*y[t-1].
// x: [B, C, T] f32, weights: [C] f32 (clamped to [0,1]). B=16, C=512, T=4096.
//
// One 64-lane wave per row. Row split into 16 chunks of 256 elements; lane l
// owns float4 at element 256k + 4l (every load/store instruction is perfectly
// coalesced: 64 lanes x 16B contiguous). All 16 loads issued up front (16 KB
// MLP per wave). Scan phases:
//   1a. per-lane 3-FMA local scan (zero incoming carry)
//   1b. 64-lane weighted Hillis-Steele scan (step weight a^4), 16 chunks
//       interleaved per step so the 6 dependent shuffle steps pipeline.
//   2+3 fused: running chunk-carry Ek (weight a^256) + per-chunk fixup
//       y_j = l_j + a^(j+1) * P, coalesced store.
// No LDS, no __syncthreads, no block-level coupling.
//
// NOTE: chunk totals are broadcast with __shfl(.,63,64), NOT
// __builtin_amdgcn_readlane — the raw builtin is i32-typed and silently
// VALUE-converts (truncates) a float argument. That was round-5's bug.

constexpr int T_LEN = 4096;
constexpr int C_LEN = 512;
constexpr int WAVES_PER_BLOCK = 4;
constexpr int BLOCK = 64 * WAVES_PER_BLOCK;   // 256
constexpr int CHUNKS = 16;                    // 16 x 256 = 4096

__global__ __launch_bounds__(BLOCK, 4) void ema_wave_kernel(
    const float* __restrict__ x,
    const float* __restrict__ w,
    float* __restrict__ y)
{
    const int wave = threadIdx.x >> 6;
    const int lane = threadIdx.x & 63;
    const int row  = blockIdx.x * WAVES_PER_BLOCK + wave;   // b*C + c
    const int c    = row & (C_LEN - 1);

    float s = w[c];
    s = fminf(fmaxf(s, 0.0f), 1.0f);
    const float a = 1.0f - s;

    const float4* xp = (const float4*)(x + (size_t)row * T_LEN);
    float4*       yp = (float4*)(y + (size_t)row * T_LEN);

    // ---- issue all 16 coalesced loads up front ----
    float4 v[CHUNKS];
    #pragma unroll
    for (int k = 0; k < CHUNKS; ++k)
        v[k] = xp[(k << 6) + lane];

    const float a2 = a * a, a3 = a2 * a, a4 = a2 * a2;

    // ---- phase 1a: per-lane local scans (zero incoming carry) ----
    float S[CHUNKS];
    #pragma unroll
    for (int k = 0; k < CHUNKS; ++k) {
        float l0 = s * v[k].x;
        if (k == 0 && lane == 0) l0 = v[0].x;   // y0 = x0 identity
        float l1 = fmaf(a, l0, s * v[k].y);
        float l2 = fmaf(a, l1, s * v[k].z);
        float l3 = fmaf(a, l2, s * v[k].w);
        v[k].x = l0; v[k].y = l1; v[k].z = l2; v[k].w = l3;
        S[k] = l3;
    }

    // ---- phase 1b: weighted Hillis-Steele over 64 lanes, chunks interleaved ----
    float wgt = a4;
    #pragma unroll
    for (int d = 1; d < 64; d <<= 1) {
        #pragma unroll
        for (int k = 0; k < CHUNKS; ++k) {
            float up = __shfl_up(S[k], d, 64);
            if (lane >= d) S[k] = fmaf(wgt, up, S[k]);
        }
        wgt *= wgt;
    }
    const float a256 = wgt;   // a^4 squared 6 times = a^256

    // (a^4)^lane for carry injection
    float powl = 1.0f, tq = a4;
    #pragma unroll
    for (int b = 0; b < 6; ++b) {
        if ((lane >> b) & 1) powl *= tq;
        tq *= tq;
    }

    // ---- phases 2+3 fused: running chunk carry + fixup + coalesced store ----
    float Ek = 0.0f;   // EMA state at end of previous chunk
    #pragma unroll
    for (int k = 0; k < CHUNKS; ++k) {
        float Sx = __shfl_up(S[k], 1, 64);
        float base = (lane == 0) ? 0.0f : Sx;      // within-chunk excl prefix
        float P = fmaf(powl, Ek, base);            // carry into this lane
        float4 o;
        o.x = fmaf(a,  P, v[k].x);
        o.y = fmaf(a2, P, v[k].y);
        o.z = fmaf(a3, P, v[k].z);
        o.w = fmaf(a4, P, v[k].w);
        yp[(k << 6) + lane] = o;

        float Tk = __shfl(S[k], 63, 64);           // chunk total (bitcast-safe)
        Ek = fmaf(a256, Ek, Tk);
    }
}

extern "C" void kernel_launch(void* const* d_in, const int* in_sizes, int n_in,
                              void* d_out, int out_size, void* d_ws, size_t ws_size,
                              hipStream_t stream) {
    const float* x = (const float*)d_in[0];
    const float* w = (const float*)d_in[1];
    float* y = (float*)d_out;

    const int rows = out_size / T_LEN;            // B*C = 8192
    const int grid = rows / WAVES_PER_BLOCK;      // 2048
    ema_wave_kernel<<<grid, BLOCK, 0, stream>>>(x, w, y);
}

// Round 10
// 221.396 us; speedup vs baseline: 1.0633x; 1.0633x over previous
//
#include <hip/hip_runtime.h>

// EMA along T: y[0]=x[0]; y[t] = s*x[t] + (1-s)*y[t-1].
// x: [B, C, T] f32, weights: [C] f32 (clamped to [0,1]). B=16, C=512, T=4096.
//
// One 256-thread block (4 waves) per row. Each lane owns 16 elements as 4
// chunks of float4; element (k,w,l,j) = 1024k + 256w + 4l + j, so every
// load/store instruction is 64 lanes x 16B contiguous (perfectly coalesced)
// and per-lane state stays small (~45 VGPR -> 8 blocks/CU resident, and the
// 4 loads genuinely stay in flight).
//
// Scan: per-chunk 3-FMA local scan (zero-in) -> per-chunk 64-lane weighted
// Hillis-Steele (step weight a^4, chunks interleaved) -> ONE __syncthreads
// around a 16-entry LDS segment-total exchange; every lane replays the
// 16-step carry chain (weight a^256, LDS broadcast reads) keeping the 4
// values its wave needs -> fixup y_j = l_j + a^(j+1)*P with NON-TEMPORAL
// stores (y is never re-read; don't let it evict x from L3).
//
// NOTE: __builtin_nontemporal_store requires a native clang vector type —
// HIP's float4 (HIP_vector_type class) is rejected. Use ext_vector_type(4).

constexpr int T_LEN = 4096;
constexpr int C_LEN = 512;
constexpr int BLOCK = 256;            // 4 waves
constexpr int NW    = 4;              // waves per block
constexpr int CH    = 4;              // chunks per lane; 4*4*256 = 4096

typedef float nfloat4 __attribute__((ext_vector_type(4)));

__global__ __launch_bounds__(BLOCK) void ema_scan_kernel(
    const float* __restrict__ x,
    const float* __restrict__ w,
    float* __restrict__ y)
{
    const int row  = blockIdx.x;          // b*C + c
    const int c    = row & (C_LEN - 1);
    const int tid  = threadIdx.x;
    const int lane = tid & 63;
    const int wv   = tid >> 6;            // wave 0..3

    float s = w[c];
    s = fminf(fmaxf(s, 0.0f), 1.0f);
    const float a = 1.0f - s;

    const nfloat4* xp = (const nfloat4*)(x + (size_t)row * T_LEN);
    nfloat4*       yp = (nfloat4*)(y + (size_t)row * T_LEN);

    // ---- 4 coalesced loads, all issued up front ----
    nfloat4 v[CH];
    #pragma unroll
    for (int k = 0; k < CH; ++k)
        v[k] = xp[(k << 8) + (wv << 6) + lane];

    const float a2 = a * a, a3 = a2 * a, a4 = a2 * a2;

    // ---- phase 1a: per-lane local scans (zero incoming carry) ----
    float S[CH];
    #pragma unroll
    for (int k = 0; k < CH; ++k) {
        float l0 = s * v[k].x;
        if (k == 0 && tid == 0) l0 = v[0].x;      // y0 = x0 identity
        float l1 = fmaf(a, l0, s * v[k].y);
        float l2 = fmaf(a, l1, s * v[k].z);
        float l3 = fmaf(a, l2, s * v[k].w);
        v[k].x = l0; v[k].y = l1; v[k].z = l2; v[k].w = l3;
        S[k] = l3;
    }

    // ---- phase 1b: weighted Hillis-Steele over 64 lanes (wt a^4) ----
    float wgt = a4;
    #pragma unroll
    for (int d = 1; d < 64; d <<= 1) {
        #pragma unroll
        for (int k = 0; k < CH; ++k) {
            float up = __shfl_up(S[k], d, 64);
            if (lane >= d) S[k] = fmaf(wgt, up, S[k]);
        }
        wgt *= wgt;
    }
    const float a256 = wgt;   // (a^4)^64 = a^256, one segment's span

    // ---- phase 2: 16 segment totals through LDS (segment m = 4k + wv) ----
    __shared__ float tot[CH * NW];
    if (lane == 63) {
        #pragma unroll
        for (int k = 0; k < CH; ++k) tot[(k << 2) + wv] = S[k];
    }
    __syncthreads();

    // Replay the serial carry chain over the 16 ordered segments; keep the
    // incoming state for the 4 segments this wave owns (m % 4 == wv).
    float E[CH];
    {
        float R = 0.0f;
        #pragma unroll
        for (int m = 0; m < CH * NW; ++m) {
            if ((m & 3) == wv) E[m >> 2] = R;     // wave-uniform branch
            R = fmaf(a256, R, tot[m]);            // LDS broadcast read
        }
    }

    // (a^4)^lane for carry injection into mid-wave lanes
    float powl = 1.0f, tq = a4;
    #pragma unroll
    for (int b = 0; b < 6; ++b) {
        if ((lane >> b) & 1) powl *= tq;
        tq *= tq;
    }

    // ---- phase 3: fixup + non-temporal coalesced stores ----
    #pragma unroll
    for (int k = 0; k < CH; ++k) {
        float Sx   = __shfl_up(S[k], 1, 64);
        float base = (lane == 0) ? 0.0f : Sx;     // within-segment excl prefix
        float P    = fmaf(powl, E[k], base);
        nfloat4 o;
        o.x = fmaf(a,  P, v[k].x);
        o.y = fmaf(a2, P, v[k].y);
        o.z = fmaf(a3, P, v[k].z);
        o.w = fmaf(a4, P, v[k].w);
        __builtin_nontemporal_store(o, &yp[(k << 8) + (wv << 6) + lane]);
    }
}

extern "C" void kernel_launch(void* const* d_in, const int* in_sizes, int n_in,
                              void* d_out, int out_size, void* d_ws, size_t ws_size,
                              hipStream_t stream) {
    const float* x = (const float*)d_in[0];
    const float* w = (const float*)d_in[1];
    float* y = (float*)d_out;

    const int rows = out_size / T_LEN;    // B*C = 8192
    ema_scan_kernel<<<rows, BLOCK, 0, stream>>>(x, w, y);
}